// Round 5
// baseline (325.483 us; speedup 1.0000x reference)
//
#include <hip/hip_runtime.h>
#include <hip/hip_bf16.h>
#include <stdint.h>

#define EPS 1e-6f

typedef unsigned short ushort_t;
using frag  = __attribute__((ext_vector_type(8))) short;   // 8 bf16
using f32x4 = __attribute__((ext_vector_type(4))) float;   // MFMA acc
using fv4   = __attribute__((ext_vector_type(4))) float;

__device__ __forceinline__ ushort_t f2bf(float f) {
  uint32_t u = __builtin_bit_cast(uint32_t, f);
  u += 0x7FFFu + ((u >> 16) & 1u);          // round-to-nearest-even
  return (ushort_t)(u >> 16);
}

__device__ __forceinline__ frag cvt8(fv4 lo, fv4 hi) {
  frag v;
  v[0]=(short)f2bf(lo[0]); v[1]=(short)f2bf(lo[1]); v[2]=(short)f2bf(lo[2]); v[3]=(short)f2bf(lo[3]);
  v[4]=(short)f2bf(hi[0]); v[5]=(short)f2bf(hi[1]); v[6]=(short)f2bf(hi[2]); v[7]=(short)f2bf(hi[3]);
  return v;
}

// ---------------------------------------------------------------------------
// P1: normalize rows. One wave per row (512 rows).
// ---------------------------------------------------------------------------
__global__ __launch_bounds__(256) void normalize_kernel(const float* __restrict__ V,
                                                        float* __restrict__ Vn) {
  const int gw   = blockIdx.x * 4 + (threadIdx.x >> 6);
  const int lane = threadIdx.x & 63;
  const float4* src = (const float4*)(V + (size_t)gw * 512) + lane * 2;
  float4 a = src[0], c = src[1];
  float s = a.x*a.x + a.y*a.y + a.z*a.z + a.w*a.w
          + c.x*c.x + c.y*c.y + c.z*c.z + c.w*c.w;
  #pragma unroll
  for (int off = 32; off; off >>= 1) s += __shfl_xor(s, off);
  float inv = 1.f / (sqrtf(s) + EPS);
  float4 na = make_float4(a.x*inv, a.y*inv, a.z*inv, a.w*inv);
  float4 nc = make_float4(c.x*inv, c.y*inv, c.z*inv, c.w*inv);
  float4* dst = (float4*)(Vn + (size_t)gw * 512) + lane * 2;
  dst[0] = na; dst[1] = nc;
}

// ---------------------------------------------------------------------------
// P2: G[b][i][j] = <Vn_b[i], Vn_b[j]>, j>i. Block per (b,i); 4 waves split j.
// ---------------------------------------------------------------------------
__global__ __launch_bounds__(256) void gram_kernel(const float* __restrict__ Vn,
                                                   float* __restrict__ G) {
  const int gi = blockIdx.x;
  const int b = gi >> 7, i = gi & 127;
  const int w = threadIdx.x >> 6, lane = threadIdx.x & 63;
  const float4* ri = (const float4*)(Vn + (size_t)gi * 512) + lane * 2;
  float4 a0 = ri[0], a1 = ri[1];
  for (int j = i + 1 + w; j < 128; j += 4) {
    const float4* rj = (const float4*)(Vn + (size_t)(b * 128 + j) * 512) + lane * 2;
    float4 c0 = rj[0], c1 = rj[1];
    float s = a0.x*c0.x + a0.y*c0.y + a0.z*c0.z + a0.w*c0.w
            + a1.x*c1.x + a1.y*c1.y + a1.z*c1.z + a1.w*c1.w;
    #pragma unroll
    for (int off = 32; off; off >>= 1) s += __shfl_xor(s, off);
    if (lane == 0) G[(size_t)gi * 128 + j] = s;
  }
}

// ---------------------------------------------------------------------------
// P3: Tt = transpose((0.5 I + triu(G,1))^-1) per 128-block, in place over G.
// ---------------------------------------------------------------------------
__global__ __launch_bounds__(256) void trinv_kernel(float* __restrict__ GT) {
  __shared__ float Gs[128][132];
  __shared__ float Ai[64][68];
  __shared__ float Di[64][68];
  __shared__ float C1[64][68];
  const int b = blockIdx.x, tid = threadIdx.x;
  float* Gg = GT + b * 16384;

  {
    const int r = tid >> 1, h = tid & 1;
    const float4* src = (const float4*)(Gg + r * 128 + h * 64);
    float4* dst = (float4*)(&Gs[r][h * 64]);
    #pragma unroll
    for (int e = 0; e < 16; ++e) dst[e] = src[e];
  }
  __syncthreads();

  const int wave = tid >> 6, lane = tid & 63;
  if (wave < 2) {
    const int o = wave * 64;
    float t[64];
    #pragma unroll
    for (int i = 63; i >= 0; --i) {
      float s = (i == lane) ? 1.f : 0.f;
      #pragma unroll
      for (int j = i + 1; j < 64; ++j) s -= Gs[o + i][o + j] * t[j];
      t[i] = 2.f * s;
    }
    float (*OUT)[68] = wave ? Di : Ai;
    #pragma unroll
    for (int i = 0; i < 64; ++i) OUT[i][lane] = t[i];
  }
  __syncthreads();

  const int i0 = (tid >> 4) << 2;
  const int j0 = (tid & 15) << 2;

  {  // C1 = B * Di
    fv4 acc[4] = {};
    for (int l = 0; l < 64; l += 4) {
      fv4 g[4], d[4];
      #pragma unroll
      for (int r = 0; r < 4; ++r) g[r] = *(const fv4*)(&Gs[i0 + r][64 + l]);
      #pragma unroll
      for (int r = 0; r < 4; ++r) d[r] = *(const fv4*)(&Di[l + r][j0]);
      #pragma unroll
      for (int r = 0; r < 4; ++r)
        #pragma unroll
        for (int l2 = 0; l2 < 4; ++l2)
          #pragma unroll
          for (int q = 0; q < 4; ++q)
            acc[r][q] = fmaf(g[r][l2], d[l2][q], acc[r][q]);
    }
    #pragma unroll
    for (int r = 0; r < 4; ++r) *(fv4*)(&C1[i0 + r][j0]) = acc[r];
  }
  __syncthreads();

  {  // corner = -Ai*C1, write transposed
    fv4 acc[4] = {};
    for (int l = 0; l < 64; l += 4) {
      fv4 g[4], d[4];
      #pragma unroll
      for (int r = 0; r < 4; ++r) g[r] = *(const fv4*)(&Ai[i0 + r][l]);
      #pragma unroll
      for (int r = 0; r < 4; ++r) d[r] = *(const fv4*)(&C1[l + r][j0]);
      #pragma unroll
      for (int r = 0; r < 4; ++r)
        #pragma unroll
        for (int l2 = 0; l2 < 4; ++l2)
          #pragma unroll
          for (int q = 0; q < 4; ++q)
            acc[r][q] = fmaf(g[r][l2], d[l2][q], acc[r][q]);
    }
    #pragma unroll
    for (int r = 0; r < 4; ++r)
      #pragma unroll
      for (int q = 0; q < 4; ++q)
        Gg[(64 + j0 + q) * 128 + (i0 + r)] = -acc[r][q];
  }

  {
    const int j = tid >> 1, h = tid & 1;
    if (j < 64) {
      if (h == 0) { for (int i = 0; i < 64; ++i) Gg[j * 128 + i] = Ai[i][j]; }
      else        { for (int i = 0; i < 64; ++i) Gg[j * 128 + 64 + i] = 0.f; }
    } else if (h == 1) {
      for (int i = 0; i < 64; ++i) Gg[j * 128 + 64 + i] = Di[i][j - 64];
    }
  }
}

// ---------------------------------------------------------------------------
// Fused chain: block owns 2 Q-rows (256 blocks); per b:
//   P = Qt·Vn_b^T ; A = P·Tt^T ; Qt -= A·Vn_b.  Epilogue: fragment-order bf16.
// ---------------------------------------------------------------------------
__global__ __launch_bounds__(256) void chain_kernel(const float* __restrict__ Vn,
                                                    const float* __restrict__ Tt,
                                                    ushort_t* __restrict__ Qf) {
  __shared__ float Qt[2][512];
  __shared__ float Pp[4][2][64];
  __shared__ float Ps[2][128];
  __shared__ float Asm[2][128];
  const int t = threadIdx.x, w = t >> 6, lane = t & 63;
  const int m0 = blockIdx.x * 2;

  for (int idx = t; idx < 1024; idx += 256) {
    int i = idx >> 9, k = idx & 511;
    Qt[i][k] = (m0 + i == k) ? 1.f : 0.f;
  }

  for (int b = 0; b < 4; ++b) {
    if (b == 0) {
      __syncthreads();
      if (t < 128) {
        Ps[0][t] = Vn[t * 512 + m0];
        Ps[1][t] = Vn[t * 512 + m0 + 1];
      }
      __syncthreads();
    } else {
      for (int ch = 0; ch < 2; ++ch) {
        __syncthreads();
        const int n = ch * 64 + lane;
        const float* vrow = Vn + (size_t)(b * 128 + n) * 512;
        float pa[2] = {0.f, 0.f};
        #pragma unroll 8
        for (int k4 = 0; k4 < 32; ++k4) {
          int kk = w * 128 + k4 * 4;
          float4 vv = *(const float4*)(vrow + kk);
          #pragma unroll
          for (int i = 0; i < 2; ++i) {
            float4 qq = *(const float4*)(&Qt[i][kk]);
            pa[i] += qq.x*vv.x + qq.y*vv.y + qq.z*vv.z + qq.w*vv.w;
          }
        }
        #pragma unroll
        for (int i = 0; i < 2; ++i) Pp[w][i][lane] = pa[i];
        __syncthreads();
        if (w < 2)
          Ps[w][ch * 64 + lane] = Pp[0][w][lane] + Pp[1][w][lane]
                                + Pp[2][w][lane] + Pp[3][w][lane];
      }
      __syncthreads();
    }
    {
      const float* trow = Tt + b * 16384 + (t >> 1) * 128 + (t & 1) * 64;
      float aa[2] = {0.f, 0.f};
      #pragma unroll 4
      for (int j4 = 0; j4 < 16; ++j4) {
        float4 tv = *(const float4*)(trow + j4 * 4);
        int j = (t & 1) * 64 + j4 * 4;
        #pragma unroll
        for (int i = 0; i < 2; ++i) {
          float4 pv = *(const float4*)(&Ps[i][j]);
          aa[i] += pv.x*tv.x + pv.y*tv.y + pv.z*tv.z + pv.w*tv.w;
        }
      }
      #pragma unroll
      for (int i = 0; i < 2; ++i) {
        float o = __shfl_xor(aa[i], 1);
        if ((t & 1) == 0) Asm[i][t >> 1] = aa[i] + o;
      }
    }
    __syncthreads();
    {
      float acc0[2] = {0.f,0.f}, acc1[2] = {0.f,0.f};
      const float* vb = Vn + (size_t)b * 65536 + t * 2;
      #pragma unroll 4
      for (int n = 0; n < 128; ++n) {
        float2 vv = *(const float2*)(vb + (size_t)n * 512);
        #pragma unroll
        for (int i = 0; i < 2; ++i) {
          float a = Asm[i][n];
          acc0[i] = fmaf(a, vv.x, acc0[i]);
          acc1[i] = fmaf(a, vv.y, acc1[i]);
        }
      }
      #pragma unroll
      for (int i = 0; i < 2; ++i) {
        Qt[i][t * 2]     -= acc0[i];
        Qt[i][t * 2 + 1] -= acc1[i];
      }
    }
  }
  __syncthreads();
  if (t < 128) {
    int i = t >> 6, ks = (t >> 2) & 15, lg = t & 3;
    int r = m0 + i;
    int nt = r >> 4, l = lg * 16 + (r & 15);
    const float* src = &Qt[i][ks * 32 + lg * 8];
    frag v;
    #pragma unroll
    for (int j = 0; j < 8; ++j) v[j] = (short)f2bf(src[j]);
    *(frag*)(Qf + ((size_t)(ks * 32 + nt) * 64 + l) * 8) = v;
  }
}

// ---------------------------------------------------------------------------
// out[m][n] = sum_k x[m][k] * Q[n][k]   M=131072 N=512 K=512
// BM=64, BN=512 (x read once), BK=64. 8 waves, wave w -> cols [w*64,w*64+64).
// x: f32 via global_load_lds, 3x16KB buffers, depth-2 kt prefetch, granule-
// XOR-swizzled (both sides). B: direct global->reg, 3-slot half-kt stream.
// One raw s_barrier per kt; vmcnt counted, never drained in-loop.
// ---------------------------------------------------------------------------
__global__ __launch_bounds__(512) void final_gemm(const float* __restrict__ X,
                                                  const ushort_t* __restrict__ Qf,
                                                  float* __restrict__ out) {
  __shared__ __align__(16) char smem[49152];          // 3 x 16KB; epilogue overlays
  const int tid = threadIdx.x;
  const int w = tid >> 6, lane = tid & 63;
  const int m0 = blockIdx.x * 64;

  // --- staging: granule s in [0,1024): row=s>>4, phys p=s&15,
  //     logical g = p ^ xm(row), xm = ((row&7)<<1)|((row>>3)&1)
  const int r0 = tid >> 4,          p0 = tid & 15;
  const int r1 = (tid + 512) >> 4,  p1 = tid & 15;
  const int g0 = p0 ^ (((r0 & 7) << 1) | ((r0 >> 3) & 1));
  const int g1 = p1 ^ (((r1 & 7) << 1) | ((r1 >> 3) & 1));
  const float* src0 = X + (size_t)(m0 + r0) * 512 + g0 * 4;
  const float* src1 = X + (size_t)(m0 + r1) * 512 + g1 * 4;
  const int ldsb0 = w * 1024;          // wave-uniform base (HW adds lane*16)
  const int ldsb1 = 8192 + w * 1024;

  #define GLOAD(KT, BUF) do { \
    __builtin_amdgcn_global_load_lds( \
      (const __attribute__((address_space(1))) uint32_t*)(src0 + (KT) * 64), \
      (__attribute__((address_space(3))) uint32_t*)(smem + (BUF) * 16384 + ldsb0), 16, 0, 0); \
    __builtin_amdgcn_global_load_lds( \
      (const __attribute__((address_space(1))) uint32_t*)(src1 + (KT) * 64), \
      (__attribute__((address_space(3))) uint32_t*)(smem + (BUF) * 16384 + ldsb1), 16, 0, 0); \
  } while (0)

  // --- B fragments: Qf[((ks*32+nt)*64+lane)*8], nt = w*4+j
  const ushort_t* qb = Qf + ((size_t)(w * 4) * 64 + lane) * 8;
  frag bs[3][4];
  #define BLOAD(KS, SLOT) do { \
    _Pragma("unroll") \
    for (int j = 0; j < 4; ++j) \
      bs[SLOT][j] = *(const frag*)(qb + (size_t)(KS) * 16384 + j * 512); \
  } while (0)

  // --- A ds_read addressing: per mf, row = mf*16+(lane&15),
  //     byte = row*256 + ((glow ^ xm(row)) << 4), glow = (lane>>4)*2; ksl flips bit7
  int aoff[4];
  #pragma unroll
  for (int mf = 0; mf < 4; ++mf) {
    int row = mf * 16 + (lane & 15);
    int xm = ((row & 7) << 1) | ((row >> 3) & 1);
    aoff[mf] = row * 256 + ((((lane >> 4) * 2) ^ xm) << 4);
  }

  f32x4 acc[4][4];
  #pragma unroll
  for (int i = 0; i < 4; ++i)
    #pragma unroll
    for (int j = 0; j < 4; ++j) acc[i][j] = (f32x4){0.f, 0.f, 0.f, 0.f};

  // prologue
  GLOAD(0, 0); GLOAD(1, 1); BLOAD(0, 0); BLOAD(1, 1);
  asm volatile("s_waitcnt vmcnt(10)" ::: "memory");   // drain g(0) only
  __builtin_amdgcn_s_barrier();

  #pragma unroll
  for (int kt = 0; kt < 8; ++kt) {
    const char* bb = smem + (kt % 3) * 16384;
    if (kt < 6) GLOAD(kt + 2, (kt + 2) % 3);
    // half 0 : uses bs[(2kt)%3]
    if (kt < 7) BLOAD(2 * kt + 2, (2 * kt + 2) % 3);
    {
      frag a_[4];
      #pragma unroll
      for (int mf = 0; mf < 4; ++mf) {
        fv4 lo = *(const fv4*)(bb + aoff[mf]);
        fv4 hi = *(const fv4*)(bb + (aoff[mf] ^ 16));
        a_[mf] = cvt8(lo, hi);
      }
      #pragma unroll
      for (int mf = 0; mf < 4; ++mf)
        #pragma unroll
        for (int j = 0; j < 4; ++j)
          acc[mf][j] = __builtin_amdgcn_mfma_f32_16x16x32_bf16(a_[mf], bs[(2 * kt) % 3][j], acc[mf][j], 0, 0, 0);
    }
    // half 1 : uses bs[(2kt+1)%3]
    if (kt < 7) BLOAD(2 * kt + 3, (2 * kt + 3) % 3);
    {
      frag a_[4];
      #pragma unroll
      for (int mf = 0; mf < 4; ++mf) {
        fv4 lo = *(const fv4*)(bb + (aoff[mf] ^ 128));
        fv4 hi = *(const fv4*)(bb + (aoff[mf] ^ 128 ^ 16));
        a_[mf] = cvt8(lo, hi);
      }
      #pragma unroll
      for (int mf = 0; mf < 4; ++mf)
        #pragma unroll
        for (int j = 0; j < 4; ++j)
          acc[mf][j] = __builtin_amdgcn_mfma_f32_16x16x32_bf16(a_[mf], bs[(2 * kt + 1) % 3][j], acc[mf][j], 0, 0, 0);
    }
    // g(kt+1) is guaranteed complete (older than b(2kt+1), in-order retire);
    // counted wait keeps g(kt+2) + next b-sets in flight.
    asm volatile("s_waitcnt vmcnt(10)" ::: "memory");
    __builtin_amdgcn_s_barrier();
  }

  // epilogue: Ep overlays smem. C/D map col=lane&15, row=(lane>>4)*4+reg
  float (*Ep)[516] = (float (*)[516])smem;
  #pragma unroll
  for (int mf = 0; mf < 4; ++mf) {
    __builtin_amdgcn_s_barrier();                     // prior readers done
    #pragma unroll
    for (int j = 0; j < 4; ++j) {
      int col = w * 64 + j * 16 + (lane & 15);
      #pragma unroll
      for (int r = 0; r < 4; ++r)
        Ep[((lane >> 4) << 2) + r][col] = acc[mf][j][r];
    }
    asm volatile("s_waitcnt lgkmcnt(0)" ::: "memory");
    __builtin_amdgcn_s_barrier();
    #pragma unroll
    for (int e = 0; e < 4; ++e) {
      int idx = e * 512 + tid;
      int rr = idx >> 7, c4 = idx & 127;
      float4 v = *(const float4*)(&Ep[rr][c4 * 4]);
      *(float4*)(out + (size_t)(m0 + mf * 16 + rr) * 512 + c4 * 4) = v;
    }
  }
  #undef GLOAD
  #undef BLOAD
}

extern "C" void kernel_launch(void* const* d_in, const int* in_sizes, int n_in,
                              void* d_out, int out_size, void* d_ws, size_t ws_size,
                              hipStream_t stream) {
  const float* x = (const float*)d_in[0];
  const float* V = (const float*)d_in[1];   // hd_vecs[0]: 512 x 512
  float* out = (float*)d_out;
  float* ws  = (float*)d_ws;

  float*    Vn = ws;                          // 262144 f32
  float*    GT = ws + 262144;                 // 65536 f32 (G -> Tt in place)
  ushort_t* Qf = (ushort_t*)(ws + 327680);    // 262144 bf16 (fragment order)

  normalize_kernel<<<128, 256, 0, stream>>>(V, Vn);
  gram_kernel<<<512, 256, 0, stream>>>(Vn, GT);
  trinv_kernel<<<4, 256, 0, stream>>>(GT);
  chain_kernel<<<256, 256, 0, stream>>>(Vn, GT, Qf);
  final_gemm<<<2048, 512, 0, stream>>>(x, Qf, out);
}

// Round 8
// 278.130 us; speedup vs baseline: 1.1703x; 1.1703x over previous
//
#include <hip/hip_runtime.h>
#include <hip/hip_bf16.h>
#include <stdint.h>

#define EPS 1e-6f

typedef unsigned short ushort_t;
using frag  = __attribute__((ext_vector_type(8))) short;   // 8 bf16
using f32x4 = __attribute__((ext_vector_type(4))) float;   // MFMA acc
using fv4   = __attribute__((ext_vector_type(4))) float;

__device__ __forceinline__ ushort_t f2bf(float f) {
  uint32_t u = __builtin_bit_cast(uint32_t, f);
  u += 0x7FFFu + ((u >> 16) & 1u);          // round-to-nearest-even
  return (ushort_t)(u >> 16);
}

__device__ __forceinline__ frag cvt8(fv4 lo, fv4 hi) {
  frag v;
  v[0]=(short)f2bf(lo[0]); v[1]=(short)f2bf(lo[1]); v[2]=(short)f2bf(lo[2]); v[3]=(short)f2bf(lo[3]);
  v[4]=(short)f2bf(hi[0]); v[5]=(short)f2bf(hi[1]); v[6]=(short)f2bf(hi[2]); v[7]=(short)f2bf(hi[3]);
  return v;
}

// ---------------------------------------------------------------------------
// P1: normalize rows. One wave per row (512 rows).
// ---------------------------------------------------------------------------
__global__ __launch_bounds__(256) void normalize_kernel(const float* __restrict__ V,
                                                        float* __restrict__ Vn) {
  const int gw   = blockIdx.x * 4 + (threadIdx.x >> 6);
  const int lane = threadIdx.x & 63;
  const float4* src = (const float4*)(V + (size_t)gw * 512) + lane * 2;
  float4 a = src[0], c = src[1];
  float s = a.x*a.x + a.y*a.y + a.z*a.z + a.w*a.w
          + c.x*c.x + c.y*c.y + c.z*c.z + c.w*c.w;
  #pragma unroll
  for (int off = 32; off; off >>= 1) s += __shfl_xor(s, off);
  float inv = 1.f / (sqrtf(s) + EPS);
  float4 na = make_float4(a.x*inv, a.y*inv, a.z*inv, a.w*inv);
  float4 nc = make_float4(c.x*inv, c.y*inv, c.z*inv, c.w*inv);
  float4* dst = (float4*)(Vn + (size_t)gw * 512) + lane * 2;
  dst[0] = na; dst[1] = nc;
}

// ---------------------------------------------------------------------------
// P2: G[b][i][j] = <Vn_b[i], Vn_b[j]>, j>i. Block per (b,i); 4 waves split j.
// ---------------------------------------------------------------------------
__global__ __launch_bounds__(256) void gram_kernel(const float* __restrict__ Vn,
                                                   float* __restrict__ G) {
  const int gi = blockIdx.x;
  const int b = gi >> 7, i = gi & 127;
  const int w = threadIdx.x >> 6, lane = threadIdx.x & 63;
  const float4* ri = (const float4*)(Vn + (size_t)gi * 512) + lane * 2;
  float4 a0 = ri[0], a1 = ri[1];
  for (int j = i + 1 + w; j < 128; j += 4) {
    const float4* rj = (const float4*)(Vn + (size_t)(b * 128 + j) * 512) + lane * 2;
    float4 c0 = rj[0], c1 = rj[1];
    float s = a0.x*c0.x + a0.y*c0.y + a0.z*c0.z + a0.w*c0.w
            + a1.x*c1.x + a1.y*c1.y + a1.z*c1.z + a1.w*c1.w;
    #pragma unroll
    for (int off = 32; off; off >>= 1) s += __shfl_xor(s, off);
    if (lane == 0) G[(size_t)gi * 128 + j] = s;
  }
}

// ---------------------------------------------------------------------------
// P3: Tt = transpose((0.5 I + triu(G,1))^-1) per 128-block, in place over G.
// ---------------------------------------------------------------------------
__global__ __launch_bounds__(256) void trinv_kernel(float* __restrict__ GT) {
  __shared__ float Gs[128][132];
  __shared__ float Ai[64][68];
  __shared__ float Di[64][68];
  __shared__ float C1[64][68];
  const int b = blockIdx.x, tid = threadIdx.x;
  float* Gg = GT + b * 16384;

  {
    const int r = tid >> 1, h = tid & 1;
    const float4* src = (const float4*)(Gg + r * 128 + h * 64);
    float4* dst = (float4*)(&Gs[r][h * 64]);
    #pragma unroll
    for (int e = 0; e < 16; ++e) dst[e] = src[e];
  }
  __syncthreads();

  const int wave = tid >> 6, lane = tid & 63;
  if (wave < 2) {
    const int o = wave * 64;
    float t[64];
    #pragma unroll
    for (int i = 63; i >= 0; --i) {
      float s = (i == lane) ? 1.f : 0.f;
      #pragma unroll
      for (int j = i + 1; j < 64; ++j) s -= Gs[o + i][o + j] * t[j];
      t[i] = 2.f * s;
    }
    float (*OUT)[68] = wave ? Di : Ai;
    #pragma unroll
    for (int i = 0; i < 64; ++i) OUT[i][lane] = t[i];
  }
  __syncthreads();

  const int i0 = (tid >> 4) << 2;
  const int j0 = (tid & 15) << 2;

  {  // C1 = B * Di
    fv4 acc[4] = {};
    for (int l = 0; l < 64; l += 4) {
      fv4 g[4], d[4];
      #pragma unroll
      for (int r = 0; r < 4; ++r) g[r] = *(const fv4*)(&Gs[i0 + r][64 + l]);
      #pragma unroll
      for (int r = 0; r < 4; ++r) d[r] = *(const fv4*)(&Di[l + r][j0]);
      #pragma unroll
      for (int r = 0; r < 4; ++r)
        #pragma unroll
        for (int l2 = 0; l2 < 4; ++l2)
          #pragma unroll
          for (int q = 0; q < 4; ++q)
            acc[r][q] = fmaf(g[r][l2], d[l2][q], acc[r][q]);
    }
    #pragma unroll
    for (int r = 0; r < 4; ++r) *(fv4*)(&C1[i0 + r][j0]) = acc[r];
  }
  __syncthreads();

  {  // corner = -Ai*C1, write transposed
    fv4 acc[4] = {};
    for (int l = 0; l < 64; l += 4) {
      fv4 g[4], d[4];
      #pragma unroll
      for (int r = 0; r < 4; ++r) g[r] = *(const fv4*)(&Ai[i0 + r][l]);
      #pragma unroll
      for (int r = 0; r < 4; ++r) d[r] = *(const fv4*)(&C1[l + r][j0]);
      #pragma unroll
      for (int r = 0; r < 4; ++r)
        #pragma unroll
        for (int l2 = 0; l2 < 4; ++l2)
          #pragma unroll
          for (int q = 0; q < 4; ++q)
            acc[r][q] = fmaf(g[r][l2], d[l2][q], acc[r][q]);
    }
    #pragma unroll
    for (int r = 0; r < 4; ++r)
      #pragma unroll
      for (int q = 0; q < 4; ++q)
        Gg[(64 + j0 + q) * 128 + (i0 + r)] = -acc[r][q];
  }

  {
    const int j = tid >> 1, h = tid & 1;
    if (j < 64) {
      if (h == 0) { for (int i = 0; i < 64; ++i) Gg[j * 128 + i] = Ai[i][j]; }
      else        { for (int i = 0; i < 64; ++i) Gg[j * 128 + 64 + i] = 0.f; }
    } else if (h == 1) {
      for (int i = 0; i < 64; ++i) Gg[j * 128 + 64 + i] = Di[i][j - 64];
    }
  }
}

// ---------------------------------------------------------------------------
// Fused chain (R4-passing version: 4 rows/block, 128 blocks): per b:
//   P = Qt·Vn_b^T ; A = P·Tt^T ; Qt -= A·Vn_b.  Epilogue: fragment-order bf16.
// ---------------------------------------------------------------------------
__global__ __launch_bounds__(256) void chain_kernel(const float* __restrict__ Vn,
                                                    const float* __restrict__ Tt,
                                                    ushort_t* __restrict__ Qf) {
  __shared__ float Qt[4][512];
  __shared__ float Pp[4][4][64];
  __shared__ float Ps[4][128];
  __shared__ float Asm[4][128];
  const int t = threadIdx.x, w = t >> 6, lane = t & 63;
  const int m0 = blockIdx.x * 4;

  for (int idx = t; idx < 2048; idx += 256) {
    int i = idx >> 9, k = idx & 511;
    Qt[i][k] = (m0 + i == k) ? 1.f : 0.f;
  }

  for (int b = 0; b < 4; ++b) {
    if (b == 0) {
      __syncthreads();
      if (t < 128) {
        #pragma unroll
        for (int i = 0; i < 4; ++i) Ps[i][t] = Vn[t * 512 + m0 + i];
      }
      __syncthreads();
    } else {
      for (int ch = 0; ch < 2; ++ch) {
        __syncthreads();
        const int n = ch * 64 + lane;
        const float* vrow = Vn + (size_t)(b * 128 + n) * 512;
        float pa[4] = {0.f, 0.f, 0.f, 0.f};
        #pragma unroll 8
        for (int k4 = 0; k4 < 32; ++k4) {
          int kk = w * 128 + k4 * 4;
          float4 vv = *(const float4*)(vrow + kk);
          #pragma unroll
          for (int i = 0; i < 4; ++i) {
            float4 qq = *(const float4*)(&Qt[i][kk]);
            pa[i] += qq.x*vv.x + qq.y*vv.y + qq.z*vv.z + qq.w*vv.w;
          }
        }
        #pragma unroll
        for (int i = 0; i < 4; ++i) Pp[w][i][lane] = pa[i];
        __syncthreads();
        if (w < 2) {
          #pragma unroll
          for (int i2 = 0; i2 < 2; ++i2) {
            int i = w * 2 + i2;
            Ps[i][ch * 64 + lane] = Pp[0][i][lane] + Pp[1][i][lane]
                                  + Pp[2][i][lane] + Pp[3][i][lane];
          }
        }
      }
      __syncthreads();
    }
    {
      const float* trow = Tt + b * 16384 + (t >> 1) * 128 + (t & 1) * 64;
      float aa[4] = {0.f, 0.f, 0.f, 0.f};
      #pragma unroll 4
      for (int j4 = 0; j4 < 16; ++j4) {
        float4 tv = *(const float4*)(trow + j4 * 4);
        int j = (t & 1) * 64 + j4 * 4;
        #pragma unroll
        for (int i = 0; i < 4; ++i) {
          float4 pv = *(const float4*)(&Ps[i][j]);
          aa[i] += pv.x*tv.x + pv.y*tv.y + pv.z*tv.z + pv.w*tv.w;
        }
      }
      #pragma unroll
      for (int i = 0; i < 4; ++i) {
        float o = __shfl_xor(aa[i], 1);
        if ((t & 1) == 0) Asm[i][t >> 1] = aa[i] + o;
      }
    }
    __syncthreads();
    {
      float acc0[4] = {0.f,0.f,0.f,0.f}, acc1[4] = {0.f,0.f,0.f,0.f};
      const float* vb = Vn + (size_t)b * 65536 + t * 2;
      #pragma unroll 4
      for (int n = 0; n < 128; ++n) {
        float2 vv = *(const float2*)(vb + (size_t)n * 512);
        #pragma unroll
        for (int i = 0; i < 4; ++i) {
          float a = Asm[i][n];
          acc0[i] = fmaf(a, vv.x, acc0[i]);
          acc1[i] = fmaf(a, vv.y, acc1[i]);
        }
      }
      #pragma unroll
      for (int i = 0; i < 4; ++i) {
        Qt[i][t * 2]     -= acc0[i];
        Qt[i][t * 2 + 1] -= acc1[i];
      }
    }
  }
  __syncthreads();
  {
    int i = t >> 6, ks = (t >> 2) & 15, lg = t & 3;
    int r = m0 + i;
    int nt = r >> 4, l = lg * 16 + (r & 15);
    const float* src = &Qt[i][ks * 32 + lg * 8];
    frag v;
    #pragma unroll
    for (int j = 0; j < 8; ++j) v[j] = (short)f2bf(src[j]);
    *(frag*)(Qf + ((size_t)(ks * 32 + nt) * 64 + l) * 8) = v;
  }
}

// ---------------------------------------------------------------------------
// out[m][n] = sum_k x[m][k] * Q[n][k]   M=131072 N=512 K=512
// R5-PASSING VERSION (unchanged). BM=64, BN=512, BK=64. 8 waves.
// x: f32 via global_load_lds, 3x16KB buffers, depth-2 kt prefetch, granule-
// XOR-swizzled (both sides). B: direct global->reg, 3-slot half-kt stream.
// One raw s_barrier per kt; vmcnt counted (10), never drained in-loop.
// ---------------------------------------------------------------------------
__global__ __launch_bounds__(512) void final_gemm(const float* __restrict__ X,
                                                  const ushort_t* __restrict__ Qf,
                                                  float* __restrict__ out) {
  __shared__ __align__(16) char smem[49152];          // 3 x 16KB; epilogue overlays
  const int tid = threadIdx.x;
  const int w = tid >> 6, lane = tid & 63;
  const int m0 = blockIdx.x * 64;

  // staging: granule s in [0,1024): row=s>>4, phys p=s&15, logical g=p^xm(row)
  const int r0 = tid >> 4,          p0 = tid & 15;
  const int r1 = (tid + 512) >> 4,  p1 = tid & 15;
  const int g0 = p0 ^ (((r0 & 7) << 1) | ((r0 >> 3) & 1));
  const int g1 = p1 ^ (((r1 & 7) << 1) | ((r1 >> 3) & 1));
  const float* src0 = X + (size_t)(m0 + r0) * 512 + g0 * 4;
  const float* src1 = X + (size_t)(m0 + r1) * 512 + g1 * 4;
  const int ldsb0 = w * 1024;          // wave-uniform base (HW adds lane*16)
  const int ldsb1 = 8192 + w * 1024;

  #define GLOAD(KT, BUF) do { \
    __builtin_amdgcn_global_load_lds( \
      (const __attribute__((address_space(1))) uint32_t*)(src0 + (KT) * 64), \
      (__attribute__((address_space(3))) uint32_t*)(smem + (BUF) * 16384 + ldsb0), 16, 0, 0); \
    __builtin_amdgcn_global_load_lds( \
      (const __attribute__((address_space(1))) uint32_t*)(src1 + (KT) * 64), \
      (__attribute__((address_space(3))) uint32_t*)(smem + (BUF) * 16384 + ldsb1), 16, 0, 0); \
  } while (0)

  // B fragments: Qf[((ks*32+nt)*64+lane)*8], nt = w*4+j
  const ushort_t* qb = Qf + ((size_t)(w * 4) * 64 + lane) * 8;
  frag bs[3][4];
  #define BLOAD(KS, SLOT) do { \
    _Pragma("unroll") \
    for (int j = 0; j < 4; ++j) \
      bs[SLOT][j] = *(const frag*)(qb + (size_t)(KS) * 16384 + j * 512); \
  } while (0)

  // A ds_read addressing: row = mf*16+(lane&15), glow = (lane>>4)*2
  int aoff[4];
  #pragma unroll
  for (int mf = 0; mf < 4; ++mf) {
    int row = mf * 16 + (lane & 15);
    int xm = ((row & 7) << 1) | ((row >> 3) & 1);
    aoff[mf] = row * 256 + ((((lane >> 4) * 2) ^ xm) << 4);
  }

  f32x4 acc[4][4];
  #pragma unroll
  for (int i = 0; i < 4; ++i)
    #pragma unroll
    for (int j = 0; j < 4; ++j) acc[i][j] = (f32x4){0.f, 0.f, 0.f, 0.f};

  // prologue
  GLOAD(0, 0); GLOAD(1, 1); BLOAD(0, 0); BLOAD(1, 1);
  asm volatile("s_waitcnt vmcnt(10)" ::: "memory");   // drain g(0) only
  __builtin_amdgcn_s_barrier();

  #pragma unroll
  for (int kt = 0; kt < 8; ++kt) {
    const char* bb = smem + (kt % 3) * 16384;
    if (kt < 6) GLOAD(kt + 2, (kt + 2) % 3);
    // half 0 : uses bs[(2kt)%3]
    if (kt < 7) BLOAD(2 * kt + 2, (2 * kt + 2) % 3);
    {
      frag a_[4];
      #pragma unroll
      for (int mf = 0; mf < 4; ++mf) {
        fv4 lo = *(const fv4*)(bb + aoff[mf]);
        fv4 hi = *(const fv4*)(bb + (aoff[mf] ^ 16));
        a_[mf] = cvt8(lo, hi);
      }
      #pragma unroll
      for (int mf = 0; mf < 4; ++mf)
        #pragma unroll
        for (int j = 0; j < 4; ++j)
          acc[mf][j] = __builtin_amdgcn_mfma_f32_16x16x32_bf16(a_[mf], bs[(2 * kt) % 3][j], acc[mf][j], 0, 0, 0);
    }
    // half 1 : uses bs[(2kt+1)%3]
    if (kt < 7) BLOAD(2 * kt + 3, (2 * kt + 3) % 3);
    {
      frag a_[4];
      #pragma unroll
      for (int mf = 0; mf < 4; ++mf) {
        fv4 lo = *(const fv4*)(bb + (aoff[mf] ^ 128));
        fv4 hi = *(const fv4*)(bb + (aoff[mf] ^ 128 ^ 16));
        a_[mf] = cvt8(lo, hi);
      }
      #pragma unroll
      for (int mf = 0; mf < 4; ++mf)
        #pragma unroll
        for (int j = 0; j < 4; ++j)
          acc[mf][j] = __builtin_amdgcn_mfma_f32_16x16x32_bf16(a_[mf], bs[(2 * kt + 1) % 3][j], acc[mf][j], 0, 0, 0);
    }
    // g(kt+1) complete (older than bs-set(kt), already auto-waited); keep
    // g(kt+2)+B(kt+1) = 10 in flight across the barrier.
    asm volatile("s_waitcnt vmcnt(10)" ::: "memory");
    __builtin_amdgcn_s_barrier();
  }

  // epilogue: Ep overlays smem. C/D map col=lane&15, row=(lane>>4)*4+reg
  float (*Ep)[516] = (float (*)[516])smem;
  #pragma unroll
  for (int mf = 0; mf < 4; ++mf) {
    __builtin_amdgcn_s_barrier();                     // prior readers done
    #pragma unroll
    for (int j = 0; j < 4; ++j) {
      int col = w * 64 + j * 16 + (lane & 15);
      #pragma unroll
      for (int r = 0; r < 4; ++r)
        Ep[((lane >> 4) << 2) + r][col] = acc[mf][j][r];
    }
    asm volatile("s_waitcnt lgkmcnt(0)" ::: "memory");
    __builtin_amdgcn_s_barrier();
    #pragma unroll
    for (int e = 0; e < 4; ++e) {
      int idx = e * 512 + tid;
      int rr = idx >> 7, c4 = idx & 127;
      float4 v = *(const float4*)(&Ep[rr][c4 * 4]);
      *(float4*)(out + (size_t)(m0 + mf * 16 + rr) * 512 + c4 * 4) = v;
    }
  }
  #undef GLOAD
  #undef BLOAD
}

extern "C" void kernel_launch(void* const* d_in, const int* in_sizes, int n_in,
                              void* d_out, int out_size, void* d_ws, size_t ws_size,
                              hipStream_t stream) {
  const float* x = (const float*)d_in[0];
  const float* V = (const float*)d_in[1];   // hd_vecs[0]: 512 x 512
  float* out = (float*)d_out;
  float* ws  = (float*)d_ws;

  float*    Vn = ws;                          // 262144 f32
  float*    GT = ws + 262144;                 // 65536 f32 (G -> Tt in place)
  ushort_t* Qf = (ushort_t*)(ws + 327680);    // 262144 bf16 (fragment order)

  normalize_kernel<<<128, 256, 0, stream>>>(V, Vn);
  gram_kernel<<<512, 256, 0, stream>>>(Vn, GT);
  trinv_kernel<<<4, 256, 0, stream>>>(GT);
  chain_kernel<<<128, 256, 0, stream>>>(Vn, GT, Qf);
  final_gemm<<<2048, 512, 0, stream>>>(x, Qf, out);
}